// Round 12
// baseline (290.837 us; speedup 1.0000x reference)
//
#include <hip/hip_runtime.h>
#include <hip/hip_fp16.h>
#include <cstddef>

#define H 128
#define E_ 30
#define T_ 60
#define DF 6

typedef unsigned int u32;
typedef __attribute__((ext_vector_type(8))) short short8;
typedef __attribute__((ext_vector_type(4))) float f32x4;

// ---- workspace layout (float offsets) ----
#define OFF_PACK   0          // uint4[8*39*64] fp16 weights
#define OFF_WFCT   79872      // Wfc^T [128][128]
#define OFF_HID    96256      // hidden [8192][128]
#define OFF_SX     1144832
#define OFF_IDV    1153024
#define OFF_AGG    1161216
#define OFF_DE     1165056
#define OFF_S      1165088
#define OFF_CC     1168992
#define OFF_WV1    1169024
#define OFF_WV2    1169152
#define ZERO_CNT   7712       // agg+de+S contiguous

__device__ __forceinline__ unsigned short f2h(float f) {
    return __half_as_ushort(__float2half(f));
}

// ------------------------------------------------------------------ fused prep
__global__ void k_prep_all(const float* __restrict__ Wih0, const float* __restrict__ Whh0,
                           const float* __restrict__ Wih1, const float* __restrict__ Whh1,
                           const float* __restrict__ Wfc, const float* __restrict__ Wt,
                           const float* __restrict__ bt, const float* __restrict__ a,
                           uint4* __restrict__ pack, float* __restrict__ WfcT,
                           float* __restrict__ wv1, float* __restrict__ wv2,
                           float* __restrict__ cc, float* __restrict__ zbase)
{
    int b = blockIdx.x;
    if (b < 78) {
        int u = b * 256 + threadIdx.x;
        int lane = u & 63;
        int s = (u >> 6) % 39;
        int j = (u >> 6) / 39;
        int hc = j * 16 + (lane & 15);
        int g = lane >> 4;
        int layer, gate, kt;
        if (s < 5)       { layer = 0; gate = 0; kt = s; }
        else if (s < 10) { layer = 0; gate = 1; kt = s - 5; }
        else if (s < 14) { layer = 0; gate = 2; kt = s - 10; }
        else if (s < 15) { layer = 0; gate = 3; kt = 0; }
        else if (s < 23) { layer = 1; gate = 0; kt = s - 15; }
        else if (s < 31) { layer = 1; gate = 1; kt = s - 23; }
        else if (s < 35) { layer = 1; gate = 2; kt = s - 31; }
        else             { layer = 1; gate = 3; kt = s - 35; }
        u32 wd[4];
        for (int p = 0; p < 4; ++p) {
            unsigned short hh[2];
            for (int q = 0; q < 2; ++q) {
                int k = kt * 32 + g * 8 + p * 2 + q;
                float v = 0.f;
                if (layer == 0) {
                    if (gate <= 1) {
                        int row = gate * 128 + hc;
                        if (k < 128) v = Whh0[row * 128 + k];
                        else if (k < 134) v = Wih0[row * 6 + (k - 128)];
                    } else if (gate == 2) {
                        v = Whh0[(256 + hc) * 128 + k];
                    } else {
                        if (k < 6) v = Wih0[(256 + hc) * 6 + k];
                    }
                } else {
                    if (gate <= 1) {
                        int row = gate * 128 + hc;
                        v = (k < 128) ? Wih1[row * 128 + k] : Whh1[row * 128 + (k - 128)];
                    } else if (gate == 2) {
                        v = Whh1[(256 + hc) * 128 + k];
                    } else {
                        v = Wih1[(256 + hc) * 128 + k];
                    }
                }
                hh[q] = f2h(v);
            }
            wd[p] = (u32)hh[0] | ((u32)hh[1] << 16);
        }
        pack[(j * 39 + s) * 64 + lane] = make_uint4(wd[0], wd[1], wd[2], wd[3]);
    } else if (b < 142) {
        int i = (b - 78) * 256 + threadIdx.x;
        int col = i / 128, h = i % 128;
        WfcT[h * 128 + col] = Wfc[i];
    } else if (b == 142) {
        int i = threadIdx.x;
        if (i < 128) {
            float s1 = 0.f, s2 = 0.f;
            for (int k = 0; k < H; ++k) {
                float w = Wt[(size_t)k * H + i];
                s1 += w * a[k];
                s2 += w * a[H + k];
            }
            wv1[i] = s1;
            wv2[i] = s2;
            if (i == 0) {
                float c1 = 0.f, c2 = 0.f;
                for (int k = 0; k < H; ++k) { c1 += bt[k] * a[k]; c2 += bt[k] * a[H + k]; }
                cc[0] = c1; cc[1] = c2;
            }
        }
    } else {
        int i = (b - 143) * 256 + threadIdx.x;
        if (i < ZERO_CNT) zbase[i] = 0.f;
    }
}

// ------------------------------------------------------------------ fused 2-layer GRU (MFMA fp16)
// R7-exact frame: 512 thr, 2 waves/SIMD, single loop body, wave-uniform
// guards, ONE barrier/step, sched_barrier(0) phase fences (the proven
// no-spill discipline). Register-neutral micro-opts kept from R11:
// biases folded into accumulator init; batched 2-sigmoid reciprocal.
#define MFMA16 __builtin_amdgcn_mfma_f32_16x16x32_f16
#define BC8(v) __builtin_bit_cast(short8, v)
#define HSW(ROW, COL) ((((ROW)) << 8) + ((((COL) >> 3) ^ ((ROW) & 15)) << 4) + (((COL) & 7) << 1))

__global__ __launch_bounds__(512, 2) void k_gru(
    const float* __restrict__ x,
    const uint4* __restrict__ pack,
    const float* __restrict__ bih0, const float* __restrict__ bhh0,
    const float* __restrict__ bih1, const float* __restrict__ bhh1,
    float* __restrict__ hidden)
{
    extern __shared__ char smem[];
    // [0,16384): h0[2][32][128]f16  [16384,32768): h1[2]  [32768,65024): x[63][32]x16B
    const int tid = threadIdx.x;
    const int lane = tid & 63;
    const int j = tid >> 6;
    const int xr = lane & 15;
    const int g = lane >> 4;
    const int hc = (j << 4) + xr;
    const int n0 = blockIdx.x << 5;

    for (int c = tid; c < 32 * 60; c += 512) {
        int r = c / 60, t = c % 60;
        const float* xp = x + (size_t)(n0 + r) * (T_ * DF) + t * DF;
        u32 w0 = (u32)f2h(xp[0]) | ((u32)f2h(xp[1]) << 16);
        u32 w1 = (u32)f2h(xp[2]) | ((u32)f2h(xp[3]) << 16);
        u32 w2 = (u32)f2h(xp[4]) | ((u32)f2h(xp[5]) << 16);
        *(uint4*)(smem + 32768 + t * 512 + r * 16) = make_uint4(w0, w1, w2, 0u);
    }
    for (int i = tid; i < 384; i += 512) ((u32*)(smem + 32768 + 30720))[i] = 0u;
    for (int i = tid; i < 4096; i += 512) {
        ((u32*)smem)[i] = 0u;
        ((u32*)(smem + 16384))[i] = 0u;
    }

    uint4 wv[39];
#pragma unroll
    for (int s = 0; s < 39; ++s) wv[s] = pack[((j * 39 + s) << 6) + lane];

    const float br0 = bih0[hc] + bhh0[hc];
    const float bz0 = bih0[H + hc] + bhh0[H + hc];
    const float bgn0 = bhh0[2 * H + hc];
    const float bgi0 = bih0[2 * H + hc];
    const float br1 = bih1[hc] + bhh1[hc];
    const float bz1 = bih1[H + hc] + bhh1[H + hc];
    const float bgn1 = bhh1[2 * H + hc];
    const float bgi1 = bih1[2 * H + hc];

    float hs0[2][4] = {{0.f,0.f,0.f,0.f},{0.f,0.f,0.f,0.f}};
    float hs1[2][4] = {{0.f,0.f,0.f,0.f},{0.f,0.f,0.f,0.f}};

    const char* xbase = smem + 32768 + (g << 9) + (xr << 4);

    __syncthreads();

    for (int t = 0; t <= T_; ++t) {
        const int pr  = (t & 1) << 13;   // h0 write / h1 read parity (byte)
        const int prx = pr ^ 8192;       // h0 read / h1 write parity

#pragma unroll
        for (int rt = 0; rt < 2; ++rt) {
            const int rowb = ((rt << 4) + xr) << 8;

            // f0 = h0(t-1) fragments — shared by L0(t) and L1(t-1)
            uint4 f0[4];
#pragma unroll
            for (int kt = 0; kt < 4; ++kt)
                f0[kt] = *(const uint4*)(smem + prx + rowb + ((((kt << 2) | g) ^ xr) << 4));

            // ================= phase A: L0(t) complete =================
            if (t < T_) {
                f32x4 aR = {br0,br0,br0,br0}, aZ = {bz0,bz0,bz0,bz0};
                f32x4 aG = {bgn0,bgn0,bgn0,bgn0}, aI = {bgi0,bgi0,bgi0,bgi0};
#pragma unroll
                for (int kt = 0; kt < 4; ++kt) {
                    short8 av = BC8(f0[kt]);
                    aR = MFMA16(av, BC8(wv[kt]), aR, 0, 0, 0);
                    aZ = MFMA16(av, BC8(wv[5 + kt]), aZ, 0, 0, 0);
                    aG = MFMA16(av, BC8(wv[10 + kt]), aG, 0, 0, 0);
                }
                {
                    uint4 fx = *(const uint4*)(xbase + (size_t)t * 512 + rt * 256);
                    short8 xv = BC8(fx);
                    aR = MFMA16(xv, BC8(wv[4]), aR, 0, 0, 0);
                    aZ = MFMA16(xv, BC8(wv[9]), aZ, 0, 0, 0);
                    aI = MFMA16(xv, BC8(wv[14]), aI, 0, 0, 0);
                }
#pragma unroll
                for (int i = 0; i < 4; ++i) {
                    float da = 1.f + __expf(-aR[i]);
                    float db = 1.f + __expf(-aZ[i]);
                    float inv = __builtin_amdgcn_rcpf(da * db);
                    float rg = inv * db, zg = inv * da;
                    float nn = aI[i] + rg * aG[i];
                    float e2 = __expf(2.f * nn);
                    float ng = 1.f - 2.f * __builtin_amdgcn_rcpf(e2 + 1.f);
                    float hn = ng + zg * (hs0[rt][i] - ng);
                    hs0[rt][i] = hn;
                    int Rw = (rt << 4) + (g << 2) + i;
                    *(unsigned short*)(smem + pr + HSW(Rw, hc)) = f2h(hn);
                }
            }
            __builtin_amdgcn_sched_barrier(0);   // strict fence: the no-spill discipline

            // ================= phase B: L1(t-1) complete =================
            if (t > 0) {
                f32x4 cR = {br1,br1,br1,br1}, cZ = {bz1,bz1,bz1,bz1};
                f32x4 cG = {bgn1,bgn1,bgn1,bgn1}, cI = {bgi1,bgi1,bgi1,bgi1};
                // y-part: reuse f0
#pragma unroll
                for (int kt = 0; kt < 4; ++kt) {
                    short8 av = BC8(f0[kt]);
                    cR = MFMA16(av, BC8(wv[15 + kt]), cR, 0, 0, 0);
                    cZ = MFMA16(av, BC8(wv[23 + kt]), cZ, 0, 0, 0);
                    cI = MFMA16(av, BC8(wv[35 + kt]), cI, 0, 0, 0);
                }
                // h1-part: f1 = h1(t-2), read inline (short live range)
#pragma unroll
                for (int kt = 0; kt < 4; ++kt) {
                    uint4 f1 = *(const uint4*)(smem + 16384 + pr + rowb + ((((kt << 2) | g) ^ xr) << 4));
                    short8 bv = BC8(f1);
                    cR = MFMA16(bv, BC8(wv[19 + kt]), cR, 0, 0, 0);
                    cZ = MFMA16(bv, BC8(wv[27 + kt]), cZ, 0, 0, 0);
                    cG = MFMA16(bv, BC8(wv[31 + kt]), cG, 0, 0, 0);
                }
#pragma unroll
                for (int i = 0; i < 4; ++i) {
                    float da = 1.f + __expf(-cR[i]);
                    float db = 1.f + __expf(-cZ[i]);
                    float inv = __builtin_amdgcn_rcpf(da * db);
                    float rg = inv * db, zg = inv * da;
                    float nn = cI[i] + rg * cG[i];
                    float e2 = __expf(2.f * nn);
                    float ng = 1.f - 2.f * __builtin_amdgcn_rcpf(e2 + 1.f);
                    float hn = ng + zg * (hs1[rt][i] - ng);
                    hs1[rt][i] = hn;
                    int Rw = (rt << 4) + (g << 2) + i;
                    *(unsigned short*)(smem + 16384 + prx + HSW(Rw, hc)) = f2h(hn);
                }
            }
            __builtin_amdgcn_sched_barrier(0);
        }
        __syncthreads();
    }

#pragma unroll
    for (int rt = 0; rt < 2; ++rt)
#pragma unroll
        for (int i = 0; i < 4; ++i) {
            int Rw = (rt << 4) + (g << 2) + i;
            hidden[(size_t)(n0 + Rw) * H + hc] = hs1[rt][i];
        }
}

// ------------------------------------------------------------------ epilogue (R9, unchanged)
__global__ void k_stats(const float* __restrict__ hidden, const float* __restrict__ GH,
                        const float* __restrict__ wv1, const float* __restrict__ cc,
                        float* __restrict__ agg, float* __restrict__ de,
                        float* __restrict__ sx, float* __restrict__ invdv)
{
    int t = threadIdx.x;
    int nbase = blockIdx.x * 32;
    if (t < H) {
        float part[E_];
#pragma unroll
        for (int e = 0; e < E_; ++e) part[e] = 0.f;
        for (int r = 0; r < 32; ++r) {
            int n = nbase + r;
            float hv = hidden[(size_t)n * H + t];
#pragma unroll
            for (int e = 0; e < E_; ++e) part[e] += GH[(size_t)n * E_ + e] * hv;
        }
#pragma unroll
        for (int e = 0; e < E_; ++e) atomicAdd(&agg[e * H + t], part[e]);
    } else if (t < H + E_) {
        int e = t - H;
        float s = 0.f;
        for (int r = 0; r < 32; ++r) s += GH[(size_t)(nbase + r) * E_ + e];
        atomicAdd(&de[e], s);
    } else if (t >= 192) {
        int lane = t & 63;
        for (int r = 0; r < 32; ++r) {
            int n = nbase + r;
            float p = hidden[(size_t)n * H + lane] * wv1[lane]
                    + hidden[(size_t)n * H + 64 + lane] * wv1[64 + lane];
            float gg = (lane < E_) ? GH[(size_t)n * E_ + lane] : 0.f;
#pragma unroll
            for (int off = 32; off > 0; off >>= 1) {
                p += __shfl_down(p, off);
                gg += __shfl_down(gg, off);
            }
            if (lane == 0) {
                sx[n] = p + cc[0];
                float dv = 0.5f * gg;
                invdv[n] = (dv != 0.f) ? 1.f / dv : 0.f;
            }
        }
    }
}

__global__ void k_attS(const float* __restrict__ hidden, const float* __restrict__ sx,
                       const float* __restrict__ invdv, const float* __restrict__ agg,
                       const float* __restrict__ wv2, const float* __restrict__ cc,
                       float* __restrict__ S)
{
    __shared__ float att_s[32][E_];
    __shared__ float sy_s[E_];
    int t = threadIdx.x;
    if (t < E_) {
        float s = 0.f;
        for (int h = 0; h < H; ++h) s += agg[t * H + h] * wv2[h];
        sy_s[t] = s + cc[1];
    }
    __syncthreads();
    int nbase = blockIdx.x * 32;
    if (t < 32) {
        int n = nbase + t;
        float sxn = sx[n];
        float vv[E_];
        float m = -1e30f;
#pragma unroll
        for (int e = 0; e < E_; ++e) {
            float v = sxn + sy_s[e];
            v = (v >= 0.f) ? v : 0.01f * v;
            vv[e] = v;
            m = fmaxf(m, v);
        }
        float ss = 0.f;
#pragma unroll
        for (int e = 0; e < E_; ++e) { vv[e] = __expf(vv[e] - m); ss += vv[e]; }
        float sc = invdv[n] / ss;
#pragma unroll
        for (int e = 0; e < E_; ++e) att_s[t][e] = vv[e] * sc;
    }
    __syncthreads();
    if (t < H) {
        float part[E_];
#pragma unroll
        for (int e = 0; e < E_; ++e) part[e] = 0.f;
        for (int r = 0; r < 32; ++r) {
            float hv = hidden[(size_t)(nbase + r) * H + t];
#pragma unroll
            for (int e = 0; e < E_; ++e) part[e] += att_s[r][e] * hv;
        }
#pragma unroll
        for (int e = 0; e < E_; ++e) atomicAdd(&S[e * H + t], part[e]);
    }
}

__global__ __launch_bounds__(256) void k_final(
    const float* __restrict__ hidden, const float* __restrict__ sx,
    const float* __restrict__ invdv, const float* __restrict__ agg,
    const float* __restrict__ de, const float* __restrict__ S,
    const float* __restrict__ WfcT, const float* __restrict__ bfc,
    const float* __restrict__ Wout, const float* __restrict__ bout,
    const float* __restrict__ wv2, const float* __restrict__ cc,
    float* __restrict__ out)
{
    __shared__ float S_s[E_ * H];
    __shared__ float sy_s[E_], ide_s[E_];
    __shared__ float nh[4][H];
    int t = threadIdx.x;
    for (int i = t; i < E_ * H; i += 256) S_s[i] = S[i];
    if (t < E_) {
        float s = 0.f;
        for (int h = 0; h < H; ++h) s += agg[t * H + h] * wv2[h];
        sy_s[t] = s + cc[1];
        float d = de[t];
        ide_s[t] = (d != 0.f) ? 1.f / d : 0.f;
    }
    __syncthreads();
    int wvx = t >> 6, lane = t & 63;
    float wouta = Wout[lane], woutb = Wout[64 + lane];
    float bfca = bfc[lane], bfcb = bfc[64 + lane];
    float boutv = bout[0];
    for (int it = 0; it < 8; ++it) {
        int n = blockIdx.x * 32 + it * 4 + wvx;
        float sxn = sx[n];
        float idv = invdv[n];
        float vv[E_];
        float m = -1e30f;
#pragma unroll
        for (int e = 0; e < E_; ++e) {
            float v = sxn + sy_s[e];
            v = (v >= 0.f) ? v : 0.01f * v;
            vv[e] = v;
            m = fmaxf(m, v);
        }
        float ss = 0.f;
#pragma unroll
        for (int e = 0; e < E_; ++e) { vv[e] = __expf(vv[e] - m); ss += vv[e]; }
        float sc = idv / ss;
        float a0 = hidden[(size_t)n * H + lane];
        float a1 = hidden[(size_t)n * H + 64 + lane];
#pragma unroll
        for (int e = 0; e < E_; ++e) {
            float wgt = vv[e] * sc * ide_s[e];
            a0 += wgt * S_s[e * H + lane];
            a1 += wgt * S_s[e * H + 64 + lane];
        }
        nh[wvx][lane] = a0;
        nh[wvx][64 + lane] = a1;
        __syncthreads();
        float f0 = bfca, f1 = bfcb;
        for (int h = 0; h < H; h += 4) {
            float4 nv = *(const float4*)&nh[wvx][h];
            f0 += nv.x * WfcT[(h + 0) * H + lane] + nv.y * WfcT[(h + 1) * H + lane]
                + nv.z * WfcT[(h + 2) * H + lane] + nv.w * WfcT[(h + 3) * H + lane];
            f1 += nv.x * WfcT[(h + 0) * H + 64 + lane] + nv.y * WfcT[(h + 1) * H + 64 + lane]
                + nv.z * WfcT[(h + 2) * H + 64 + lane] + nv.w * WfcT[(h + 3) * H + 64 + lane];
        }
        f0 = (f0 >= 0.f) ? f0 : 0.01f * f0;
        f1 = (f1 >= 0.f) ? f1 : 0.01f * f1;
        float op = f0 * wouta + f1 * woutb;
#pragma unroll
        for (int off = 32; off > 0; off >>= 1) op += __shfl_down(op, off);
        if (lane == 0) out[n] = op + boutv;
        __syncthreads();
    }
}

// ------------------------------------------------------------------ launcher
extern "C" void kernel_launch(void* const* d_in, const int* in_sizes, int n_in,
                              void* d_out, int out_size, void* d_ws, size_t ws_size,
                              hipStream_t stream)
{
    const float* x    = (const float*)d_in[0];
    const float* GH   = (const float*)d_in[1];
    const float* Wih0 = (const float*)d_in[2];
    const float* Whh0 = (const float*)d_in[3];
    const float* bih0 = (const float*)d_in[4];
    const float* bhh0 = (const float*)d_in[5];
    const float* Wih1 = (const float*)d_in[6];
    const float* Whh1 = (const float*)d_in[7];
    const float* bih1 = (const float*)d_in[8];
    const float* bhh1 = (const float*)d_in[9];
    const float* Wt   = (const float*)d_in[10];
    const float* bt   = (const float*)d_in[11];
    const float* a    = (const float*)d_in[12];
    const float* Wfc  = (const float*)d_in[13];
    const float* bfc  = (const float*)d_in[14];
    const float* Wout = (const float*)d_in[15];
    const float* bout = (const float*)d_in[16];

    float* ws    = (float*)d_ws;
    uint4* pack  = (uint4*)(ws + OFF_PACK);
    float* WfcT  = ws + OFF_WFCT;
    float* hid   = ws + OFF_HID;
    float* sx    = ws + OFF_SX;
    float* idv   = ws + OFF_IDV;
    float* agg   = ws + OFF_AGG;
    float* de    = ws + OFF_DE;
    float* S     = ws + OFF_S;
    float* cc    = ws + OFF_CC;
    float* wv1   = ws + OFF_WV1;
    float* wv2   = ws + OFF_WV2;

    k_prep_all<<<174, 256, 0, stream>>>(Wih0, Whh0, Wih1, Whh1, Wfc, Wt, bt, a,
                                        pack, WfcT, wv1, wv2, cc, agg);

    const size_t lds_bytes = 65024;
    (void)hipFuncSetAttribute((const void*)k_gru,
                              hipFuncAttributeMaxDynamicSharedMemorySize,
                              (int)lds_bytes);
    k_gru<<<256, 512, lds_bytes, stream>>>(x, pack, bih0, bhh0, bih1, bhh1, hid);

    k_stats<<<256, 256, 0, stream>>>(hid, GH, wv1, cc, agg, de, sx, idv);
    k_attS<<<256, 256, 0, stream>>>(hid, sx, idv, agg, wv2, cc, S);
    k_final<<<256, 256, 0, stream>>>(hid, sx, idv, agg, de, S, WfcT, bfc,
                                     Wout, bout, wv2, cc, (float*)d_out);
}

// Round 13
// 241.880 us; speedup vs baseline: 1.2024x; 1.2024x over previous
//
#include <hip/hip_runtime.h>
#include <hip/hip_fp16.h>
#include <cstddef>

#define H 128
#define E_ 30
#define T_ 60
#define DF 6

typedef unsigned int u32;
typedef __attribute__((ext_vector_type(8))) short short8;
typedef __attribute__((ext_vector_type(4))) float f32x4;

// ---- workspace layout (float offsets) ----
#define OFF_PACK   0          // uint4[8*39*64] fp16 weights
#define OFF_WFCT   79872      // Wfc^T [128][128]
#define OFF_HID    96256      // hidden [8192][128]
#define OFF_SX     1144832
#define OFF_IDV    1153024
#define OFF_AGG    1161216
#define OFF_DE     1165056
#define OFF_S      1165088
#define OFF_CC     1168992
#define OFF_WV1    1169024
#define OFF_WV2    1169152
#define ZERO_CNT   7712       // agg+de+S contiguous

__device__ __forceinline__ unsigned short f2h(float f) {
    return __half_as_ushort(__float2half(f));
}

// ------------------------------------------------------------------ fused prep
__global__ void k_prep_all(const float* __restrict__ Wih0, const float* __restrict__ Whh0,
                           const float* __restrict__ Wih1, const float* __restrict__ Whh1,
                           const float* __restrict__ Wfc, const float* __restrict__ Wt,
                           const float* __restrict__ bt, const float* __restrict__ a,
                           uint4* __restrict__ pack, float* __restrict__ WfcT,
                           float* __restrict__ wv1, float* __restrict__ wv2,
                           float* __restrict__ cc, float* __restrict__ zbase)
{
    int b = blockIdx.x;
    if (b < 78) {
        int u = b * 256 + threadIdx.x;
        int lane = u & 63;
        int s = (u >> 6) % 39;
        int j = (u >> 6) / 39;
        int hc = j * 16 + (lane & 15);
        int g = lane >> 4;
        int layer, gate, kt;
        if (s < 5)       { layer = 0; gate = 0; kt = s; }
        else if (s < 10) { layer = 0; gate = 1; kt = s - 5; }
        else if (s < 14) { layer = 0; gate = 2; kt = s - 10; }
        else if (s < 15) { layer = 0; gate = 3; kt = 0; }
        else if (s < 23) { layer = 1; gate = 0; kt = s - 15; }
        else if (s < 31) { layer = 1; gate = 1; kt = s - 23; }
        else if (s < 35) { layer = 1; gate = 2; kt = s - 31; }
        else             { layer = 1; gate = 3; kt = s - 35; }
        u32 wd[4];
        for (int p = 0; p < 4; ++p) {
            unsigned short hh[2];
            for (int q = 0; q < 2; ++q) {
                int k = kt * 32 + g * 8 + p * 2 + q;
                float v = 0.f;
                if (layer == 0) {
                    if (gate <= 1) {
                        int row = gate * 128 + hc;
                        if (k < 128) v = Whh0[row * 128 + k];
                        else if (k < 134) v = Wih0[row * 6 + (k - 128)];
                    } else if (gate == 2) {
                        v = Whh0[(256 + hc) * 128 + k];
                    } else {
                        if (k < 6) v = Wih0[(256 + hc) * 6 + k];
                    }
                } else {
                    if (gate <= 1) {
                        int row = gate * 128 + hc;
                        v = (k < 128) ? Wih1[row * 128 + k] : Whh1[row * 128 + (k - 128)];
                    } else if (gate == 2) {
                        v = Whh1[(256 + hc) * 128 + k];
                    } else {
                        v = Wih1[(256 + hc) * 128 + k];
                    }
                }
                hh[q] = f2h(v);
            }
            wd[p] = (u32)hh[0] | ((u32)hh[1] << 16);
        }
        pack[(j * 39 + s) * 64 + lane] = make_uint4(wd[0], wd[1], wd[2], wd[3]);
    } else if (b < 142) {
        int i = (b - 78) * 256 + threadIdx.x;
        int col = i / 128, h = i % 128;
        WfcT[h * 128 + col] = Wfc[i];
    } else if (b == 142) {
        int i = threadIdx.x;
        if (i < 128) {
            float s1 = 0.f, s2 = 0.f;
            for (int k = 0; k < H; ++k) {
                float w = Wt[(size_t)k * H + i];
                s1 += w * a[k];
                s2 += w * a[H + k];
            }
            wv1[i] = s1;
            wv2[i] = s2;
            if (i == 0) {
                float c1 = 0.f, c2 = 0.f;
                for (int k = 0; k < H; ++k) { c1 += bt[k] * a[k]; c2 += bt[k] * a[H + k]; }
                cc[0] = c1; cc[1] = c2;
            }
        }
    } else {
        int i = (b - 143) * 256 + threadIdx.x;
        if (i < ZERO_CNT) zbase[i] = 0.f;
    }
}

// ------------------------------------------------------------------ fused 2-layer GRU (MFMA fp16)
// EXACT R7 configuration (best measured: k_gru 194us, FETCH 7.1MB, no spill).
// Skewed pipeline, ONE barrier/step. Within each rt-tile the two layers run
// as SEQUENTIAL phases (L0 mfma+act, then L1 mfma+act) separated by
// sched_barrier(0): only ONE 16-reg accumulator set live at a time.
// Zero-init accumulators; biases added post-MFMA; 3 independent rcp
// activations. Do NOT modify this instruction mix — R8/R10/R11/R12 all
// spilled from small deviations (allocator slack is ~0 at this footprint).
#define MFMA16 __builtin_amdgcn_mfma_f32_16x16x32_f16

__global__ __launch_bounds__(512, 2) void k_gru(
    const float* __restrict__ x,
    const uint4* __restrict__ pack,
    const float* __restrict__ bih0, const float* __restrict__ bhh0,
    const float* __restrict__ bih1, const float* __restrict__ bhh1,
    float* __restrict__ hidden)
{
    extern __shared__ char smem[];
    // [0,16384): h0[2][32][128]f16  [16384,32768): h1[2]  [32768,65024): x[63][32]x16B
    const int tid = threadIdx.x;
    const int lane = tid & 63;
    const int j = tid >> 6;             // wave index = hidden col group
    const int xr = lane & 15;
    const int g = lane >> 4;
    const int hc = (j << 4) + xr;       // D-fragment col (hidden unit)
    const int n0 = blockIdx.x << 5;

    // x preload: cell (r,t) = 6 fp16 + 2 zero pads, at 32768 + t*512 + r*16
    for (int c = tid; c < 32 * 60; c += 512) {
        int r = c / 60, t = c % 60;
        const float* xp = x + (size_t)(n0 + r) * (T_ * DF) + t * DF;
        u32 w0 = (u32)f2h(xp[0]) | ((u32)f2h(xp[1]) << 16);
        u32 w1 = (u32)f2h(xp[2]) | ((u32)f2h(xp[3]) << 16);
        u32 w2 = (u32)f2h(xp[4]) | ((u32)f2h(xp[5]) << 16);
        *(uint4*)(smem + 32768 + t * 512 + r * 16) = make_uint4(w0, w1, w2, 0u);
    }
    // zero x pad rows 60..62 and both parities of h buffers
    for (int i = tid; i < 384; i += 512) ((u32*)(smem + 32768 + 30720))[i] = 0u;
    for (int i = tid; i < 4096; i += 512) {
        ((u32*)smem)[i] = 0u;
        ((u32*)(smem + 16384))[i] = 0u;
    }

    uint4 wv[39];
#pragma unroll
    for (int s = 0; s < 39; ++s) wv[s] = pack[((j * 39 + s) << 6) + lane];

    const float br0 = bih0[hc] + bhh0[hc];
    const float bz0 = bih0[H + hc] + bhh0[H + hc];
    const float bgn0 = bhh0[2 * H + hc];
    const float bgi0 = bih0[2 * H + hc];
    const float br1 = bih1[hc] + bhh1[hc];
    const float bz1 = bih1[H + hc] + bhh1[H + hc];
    const float bgn1 = bhh1[2 * H + hc];
    const float bgi1 = bih1[2 * H + hc];

    float hs0[2][4] = {{0.f,0.f,0.f,0.f},{0.f,0.f,0.f,0.f}};
    float hs1[2][4] = {{0.f,0.f,0.f,0.f},{0.f,0.f,0.f,0.f}};

    // loop-invariant x fragment base (rt=1 row = +256 const offset)
    const char* xbase = smem + 32768 + (g << 9) + (xr << 4);

    __syncthreads();

    for (int t = 0; t <= T_; ++t) {
        const int pr  = (t & 1) << 13;   // h0 write / h1 read parity (byte)
        const int prx = pr ^ 8192;       // h0 read / h1 write parity

#pragma unroll
        for (int rt = 0; rt < 2; ++rt) {
            const int R = (rt << 4) + xr;
            const int rowb = R << 8;

            // f0 = h0(t-1) fragments — shared by L0(t) and L1(t-1)
            uint4 f0[4];
#pragma unroll
            for (int kt = 0; kt < 4; ++kt)
                f0[kt] = *(const uint4*)(smem + prx + rowb + ((((kt << 2) | g) ^ xr) << 4));

            // ================= phase A: L0(t) complete =================
            if (t < T_) {
                f32x4 aR = {0,0,0,0}, aZ = {0,0,0,0}, aG = {0,0,0,0}, aI = {0,0,0,0};
                uint4 fx = *(const uint4*)(xbase + (size_t)t * 512 + rt * 256);
                short8 xv = __builtin_bit_cast(short8, fx);
#pragma unroll
                for (int kt = 0; kt < 4; ++kt) {
                    short8 av = __builtin_bit_cast(short8, f0[kt]);
                    aR = MFMA16(av, __builtin_bit_cast(short8, wv[kt]), aR, 0, 0, 0);
                    aZ = MFMA16(av, __builtin_bit_cast(short8, wv[5 + kt]), aZ, 0, 0, 0);
                    aG = MFMA16(av, __builtin_bit_cast(short8, wv[10 + kt]), aG, 0, 0, 0);
                }
                aR = MFMA16(xv, __builtin_bit_cast(short8, wv[4]), aR, 0, 0, 0);
                aZ = MFMA16(xv, __builtin_bit_cast(short8, wv[9]), aZ, 0, 0, 0);
                aI = MFMA16(xv, __builtin_bit_cast(short8, wv[14]), aI, 0, 0, 0);
#pragma unroll
                for (int i = 0; i < 4; ++i) {
                    float rg = __builtin_amdgcn_rcpf(1.f + __expf(-(aR[i] + br0)));
                    float zg = __builtin_amdgcn_rcpf(1.f + __expf(-(aZ[i] + bz0)));
                    float nn = aI[i] + bgi0 + rg * (aG[i] + bgn0);
                    float e2 = __expf(2.f * nn);
                    float ng = 1.f - 2.f * __builtin_amdgcn_rcpf(e2 + 1.f);
                    float hn = ng + zg * (hs0[rt][i] - ng);
                    hs0[rt][i] = hn;
                    int Rw = (rt << 4) + (g << 2) + i;
                    *(unsigned short*)(smem + pr + (Rw << 8) + (((hc >> 3) ^ (Rw & 15)) << 4) + ((hc & 7) << 1)) = f2h(hn);
                }
            }
            __builtin_amdgcn_sched_barrier(0);

            // ================= phase B: L1(t-1) complete =================
            if (t > 0) {
                f32x4 cR = {0,0,0,0}, cZ = {0,0,0,0}, cG = {0,0,0,0}, cI = {0,0,0,0};
                // y-part: reuse f0
#pragma unroll
                for (int kt = 0; kt < 4; ++kt) {
                    short8 av = __builtin_bit_cast(short8, f0[kt]);
                    cR = MFMA16(av, __builtin_bit_cast(short8, wv[15 + kt]), cR, 0, 0, 0);
                    cZ = MFMA16(av, __builtin_bit_cast(short8, wv[23 + kt]), cZ, 0, 0, 0);
                    cI = MFMA16(av, __builtin_bit_cast(short8, wv[35 + kt]), cI, 0, 0, 0);
                }
                // h1-part: f1 = h1(t-2), read inline (short live range)
#pragma unroll
                for (int kt = 0; kt < 4; ++kt) {
                    uint4 f1 = *(const uint4*)(smem + 16384 + pr + rowb + ((((kt << 2) | g) ^ xr) << 4));
                    short8 bv = __builtin_bit_cast(short8, f1);
                    cR = MFMA16(bv, __builtin_bit_cast(short8, wv[19 + kt]), cR, 0, 0, 0);
                    cZ = MFMA16(bv, __builtin_bit_cast(short8, wv[27 + kt]), cZ, 0, 0, 0);
                    cG = MFMA16(bv, __builtin_bit_cast(short8, wv[31 + kt]), cG, 0, 0, 0);
                }
#pragma unroll
                for (int i = 0; i < 4; ++i) {
                    float rg = __builtin_amdgcn_rcpf(1.f + __expf(-(cR[i] + br1)));
                    float zg = __builtin_amdgcn_rcpf(1.f + __expf(-(cZ[i] + bz1)));
                    float nn = cI[i] + bgi1 + rg * (cG[i] + bgn1);
                    float e2 = __expf(2.f * nn);
                    float ng = 1.f - 2.f * __builtin_amdgcn_rcpf(e2 + 1.f);
                    float hn = ng + zg * (hs1[rt][i] - ng);
                    hs1[rt][i] = hn;
                    int Rw = (rt << 4) + (g << 2) + i;
                    *(unsigned short*)(smem + 16384 + prx + (Rw << 8) + (((hc >> 3) ^ (Rw & 15)) << 4) + ((hc & 7) << 1)) = f2h(hn);
                }
            }
            __builtin_amdgcn_sched_barrier(0);
        }
        __syncthreads();
    }

#pragma unroll
    for (int rt = 0; rt < 2; ++rt)
#pragma unroll
        for (int i = 0; i < 4; ++i) {
            int Rw = (rt << 4) + (g << 2) + i;
            hidden[(size_t)(n0 + Rw) * H + hc] = hs1[rt][i];
        }
}

// ------------------------------------------------------------------ epilogue (R9, unchanged)
__global__ void k_stats(const float* __restrict__ hidden, const float* __restrict__ GH,
                        const float* __restrict__ wv1, const float* __restrict__ cc,
                        float* __restrict__ agg, float* __restrict__ de,
                        float* __restrict__ sx, float* __restrict__ invdv)
{
    int t = threadIdx.x;
    int nbase = blockIdx.x * 32;
    if (t < H) {
        float part[E_];
#pragma unroll
        for (int e = 0; e < E_; ++e) part[e] = 0.f;
        for (int r = 0; r < 32; ++r) {
            int n = nbase + r;
            float hv = hidden[(size_t)n * H + t];
#pragma unroll
            for (int e = 0; e < E_; ++e) part[e] += GH[(size_t)n * E_ + e] * hv;
        }
#pragma unroll
        for (int e = 0; e < E_; ++e) atomicAdd(&agg[e * H + t], part[e]);
    } else if (t < H + E_) {
        int e = t - H;
        float s = 0.f;
        for (int r = 0; r < 32; ++r) s += GH[(size_t)(nbase + r) * E_ + e];
        atomicAdd(&de[e], s);
    } else if (t >= 192) {
        int lane = t & 63;
        for (int r = 0; r < 32; ++r) {
            int n = nbase + r;
            float p = hidden[(size_t)n * H + lane] * wv1[lane]
                    + hidden[(size_t)n * H + 64 + lane] * wv1[64 + lane];
            float gg = (lane < E_) ? GH[(size_t)n * E_ + lane] : 0.f;
#pragma unroll
            for (int off = 32; off > 0; off >>= 1) {
                p += __shfl_down(p, off);
                gg += __shfl_down(gg, off);
            }
            if (lane == 0) {
                sx[n] = p + cc[0];
                float dv = 0.5f * gg;
                invdv[n] = (dv != 0.f) ? 1.f / dv : 0.f;
            }
        }
    }
}

__global__ void k_attS(const float* __restrict__ hidden, const float* __restrict__ sx,
                       const float* __restrict__ invdv, const float* __restrict__ agg,
                       const float* __restrict__ wv2, const float* __restrict__ cc,
                       float* __restrict__ S)
{
    __shared__ float att_s[32][E_];
    __shared__ float sy_s[E_];
    int t = threadIdx.x;
    if (t < E_) {
        float s = 0.f;
        for (int h = 0; h < H; ++h) s += agg[t * H + h] * wv2[h];
        sy_s[t] = s + cc[1];
    }
    __syncthreads();
    int nbase = blockIdx.x * 32;
    if (t < 32) {
        int n = nbase + t;
        float sxn = sx[n];
        float vv[E_];
        float m = -1e30f;
#pragma unroll
        for (int e = 0; e < E_; ++e) {
            float v = sxn + sy_s[e];
            v = (v >= 0.f) ? v : 0.01f * v;
            vv[e] = v;
            m = fmaxf(m, v);
        }
        float ss = 0.f;
#pragma unroll
        for (int e = 0; e < E_; ++e) { vv[e] = __expf(vv[e] - m); ss += vv[e]; }
        float sc = invdv[n] / ss;
#pragma unroll
        for (int e = 0; e < E_; ++e) att_s[t][e] = vv[e] * sc;
    }
    __syncthreads();
    if (t < H) {
        float part[E_];
#pragma unroll
        for (int e = 0; e < E_; ++e) part[e] = 0.f;
        for (int r = 0; r < 32; ++r) {
            float hv = hidden[(size_t)(nbase + r) * H + t];
#pragma unroll
            for (int e = 0; e < E_; ++e) part[e] += att_s[r][e] * hv;
        }
#pragma unroll
        for (int e = 0; e < E_; ++e) atomicAdd(&S[e * H + t], part[e]);
    }
}

__global__ __launch_bounds__(256) void k_final(
    const float* __restrict__ hidden, const float* __restrict__ sx,
    const float* __restrict__ invdv, const float* __restrict__ agg,
    const float* __restrict__ de, const float* __restrict__ S,
    const float* __restrict__ WfcT, const float* __restrict__ bfc,
    const float* __restrict__ Wout, const float* __restrict__ bout,
    const float* __restrict__ wv2, const float* __restrict__ cc,
    float* __restrict__ out)
{
    __shared__ float S_s[E_ * H];
    __shared__ float sy_s[E_], ide_s[E_];
    __shared__ float nh[4][H];
    int t = threadIdx.x;
    for (int i = t; i < E_ * H; i += 256) S_s[i] = S[i];
    if (t < E_) {
        float s = 0.f;
        for (int h = 0; h < H; ++h) s += agg[t * H + h] * wv2[h];
        sy_s[t] = s + cc[1];
        float d = de[t];
        ide_s[t] = (d != 0.f) ? 1.f / d : 0.f;
    }
    __syncthreads();
    int wvx = t >> 6, lane = t & 63;
    float wouta = Wout[lane], woutb = Wout[64 + lane];
    float bfca = bfc[lane], bfcb = bfc[64 + lane];
    float boutv = bout[0];
    for (int it = 0; it < 8; ++it) {
        int n = blockIdx.x * 32 + it * 4 + wvx;
        float sxn = sx[n];
        float idv = invdv[n];
        float vv[E_];
        float m = -1e30f;
#pragma unroll
        for (int e = 0; e < E_; ++e) {
            float v = sxn + sy_s[e];
            v = (v >= 0.f) ? v : 0.01f * v;
            vv[e] = v;
            m = fmaxf(m, v);
        }
        float ss = 0.f;
#pragma unroll
        for (int e = 0; e < E_; ++e) { vv[e] = __expf(vv[e] - m); ss += vv[e]; }
        float sc = idv / ss;
        float a0 = hidden[(size_t)n * H + lane];
        float a1 = hidden[(size_t)n * H + 64 + lane];
#pragma unroll
        for (int e = 0; e < E_; ++e) {
            float wgt = vv[e] * sc * ide_s[e];
            a0 += wgt * S_s[e * H + lane];
            a1 += wgt * S_s[e * H + 64 + lane];
        }
        nh[wvx][lane] = a0;
        nh[wvx][64 + lane] = a1;
        __syncthreads();
        float f0 = bfca, f1 = bfcb;
        for (int h = 0; h < H; h += 4) {
            float4 nv = *(const float4*)&nh[wvx][h];
            f0 += nv.x * WfcT[(h + 0) * H + lane] + nv.y * WfcT[(h + 1) * H + lane]
                + nv.z * WfcT[(h + 2) * H + lane] + nv.w * WfcT[(h + 3) * H + lane];
            f1 += nv.x * WfcT[(h + 0) * H + 64 + lane] + nv.y * WfcT[(h + 1) * H + 64 + lane]
                + nv.z * WfcT[(h + 2) * H + 64 + lane] + nv.w * WfcT[(h + 3) * H + 64 + lane];
        }
        f0 = (f0 >= 0.f) ? f0 : 0.01f * f0;
        f1 = (f1 >= 0.f) ? f1 : 0.01f * f1;
        float op = f0 * wouta + f1 * woutb;
#pragma unroll
        for (int off = 32; off > 0; off >>= 1) op += __shfl_down(op, off);
        if (lane == 0) out[n] = op + boutv;
        __syncthreads();
    }
}

// ------------------------------------------------------------------ launcher
extern "C" void kernel_launch(void* const* d_in, const int* in_sizes, int n_in,
                              void* d_out, int out_size, void* d_ws, size_t ws_size,
                              hipStream_t stream)
{
    const float* x    = (const float*)d_in[0];
    const float* GH   = (const float*)d_in[1];
    const float* Wih0 = (const float*)d_in[2];
    const float* Whh0 = (const float*)d_in[3];
    const float* bih0 = (const float*)d_in[4];
    const float* bhh0 = (const float*)d_in[5];
    const float* Wih1 = (const float*)d_in[6];
    const float* Whh1 = (const float*)d_in[7];
    const float* bih1 = (const float*)d_in[8];
    const float* bhh1 = (const float*)d_in[9];
    const float* Wt   = (const float*)d_in[10];
    const float* bt   = (const float*)d_in[11];
    const float* a    = (const float*)d_in[12];
    const float* Wfc  = (const float*)d_in[13];
    const float* bfc  = (const float*)d_in[14];
    const float* Wout = (const float*)d_in[15];
    const float* bout = (const float*)d_in[16];

    float* ws    = (float*)d_ws;
    uint4* pack  = (uint4*)(ws + OFF_PACK);
    float* WfcT  = ws + OFF_WFCT;
    float* hid   = ws + OFF_HID;
    float* sx    = ws + OFF_SX;
    float* idv   = ws + OFF_IDV;
    float* agg   = ws + OFF_AGG;
    float* de    = ws + OFF_DE;
    float* S     = ws + OFF_S;
    float* cc    = ws + OFF_CC;
    float* wv1   = ws + OFF_WV1;
    float* wv2   = ws + OFF_WV2;

    k_prep_all<<<174, 256, 0, stream>>>(Wih0, Whh0, Wih1, Whh1, Wfc, Wt, bt, a,
                                        pack, WfcT, wv1, wv2, cc, agg);

    const size_t lds_bytes = 65024;
    (void)hipFuncSetAttribute((const void*)k_gru,
                              hipFuncAttributeMaxDynamicSharedMemorySize,
                              (int)lds_bytes);
    k_gru<<<256, 512, lds_bytes, stream>>>(x, pack, bih0, bhh0, bih1, bhh1, hid);

    k_stats<<<256, 256, 0, stream>>>(hid, GH, wv1, cc, agg, de, sx, idv);
    k_attS<<<256, 256, 0, stream>>>(hid, sx, idv, agg, wv2, cc, S);
    k_final<<<256, 256, 0, stream>>>(hid, sx, idv, agg, de, S, WfcT, bfc,
                                     Wout, bout, wv2, cc, (float*)d_out);
}